// Round 1
// baseline (62.009 us; speedup 1.0000x reference)
//
#include <hip/hip_runtime.h>

#define T 4096
#define NTHREADS 1024
#define ELEMS_PER_THREAD 4
#define MIN_GAP 5
#define MIN_SIZE 5

__global__ __launch_bounds__(NTHREADS)
void custom_loss_kernel(const float* __restrict__ w_phi,
                        const float* __restrict__ y,
                        const int* __restrict__ eps_p,
                        float* __restrict__ out) {
    const int b = blockIdx.x;
    const int t = threadIdx.x;
    const float eps = (float)eps_p[0];
    const float y0 = y[b * 2 + 0];
    const float y1 = y[b * 2 + 1];
    const float* __restrict__ x = w_phi + (size_t)b * T;

    __shared__ float sm[T];        // holds b-vector, then its suffix max
    __shared__ float wred[16];     // per-wave partial maxima

    // Step 1: compute a (registers) and b (LDS)
    float a_loc[ELEMS_PER_THREAD];
    #pragma unroll
    for (int k = 0; k < ELEMS_PER_THREAD; k++) {
        int i = t + k * NTHREADS;
        float xi = x[i];
        float fi = (float)i;
        float pi = fmaxf(0.0f, fabsf(y0 - fi) - eps);
        float pj = fmaxf(0.0f, fabsf(y1 - fi) - eps);
        a_loc[k] = xi + 0.5f * pi;
        sm[i]    = xi + 0.5f * pj;
    }
    __syncthreads();

    // Step 2: suffix-max scan (Hillis-Steele), sm[i] = max(b[i..T-1])
    for (int off = 1; off < T; off <<= 1) {
        float v[ELEMS_PER_THREAD];
        #pragma unroll
        for (int k = 0; k < ELEMS_PER_THREAD; k++) {
            int i = t + k * NTHREADS;
            float cur = sm[i];
            int j = i + off;
            if (j < T) cur = fmaxf(cur, sm[j]);
            v[k] = cur;
        }
        __syncthreads();
        #pragma unroll
        for (int k = 0; k < ELEMS_PER_THREAD; k++) {
            sm[t + k * NTHREADS] = v[k];
        }
        __syncthreads();
    }

    // Step 3: best = max over i in [MIN_GAP, T-1-MIN_SIZE] of a[i] + sm[i+MIN_SIZE]
    float best = -3.402823466e38f;
    #pragma unroll
    for (int k = 0; k < ELEMS_PER_THREAD; k++) {
        int i = t + k * NTHREADS;
        if (i >= MIN_GAP && (i + MIN_SIZE) < T) {
            best = fmaxf(best, a_loc[k] + sm[i + MIN_SIZE]);
        }
    }

    // Block reduction: wave-64 shuffle, then cross-wave via LDS
    const int lane = t & 63;
    const int wid  = t >> 6;
    #pragma unroll
    for (int off = 32; off > 0; off >>= 1) {
        best = fmaxf(best, __shfl_down(best, off, 64));
    }
    if (lane == 0) wred[wid] = best;
    __syncthreads();

    if (wid == 0) {
        float v = (lane < (NTHREADS / 64)) ? wred[lane] : -3.402823466e38f;
        #pragma unroll
        for (int off = 8; off > 0; off >>= 1) {
            v = fmaxf(v, __shfl_down(v, off, 64));
        }
        if (lane == 0) {
            // init = a[1] + b[1+MIN_SIZE]
            float a1 = x[1] + 0.5f * fmaxf(0.0f, fabsf(y0 - 1.0f) - eps);
            float b6 = x[6] + 0.5f * fmaxf(0.0f, fabsf(y1 - (float)(1 + MIN_SIZE)) - eps);
            float res = fmaxf(v, a1 + b6);
            atomicAdd(out, res * 0.125f);   // mean over B=8
        }
    }
}

extern "C" void kernel_launch(void* const* d_in, const int* in_sizes, int n_in,
                              void* d_out, int out_size, void* d_ws, size_t ws_size,
                              hipStream_t stream) {
    const float* w_phi = (const float*)d_in[0];   // (8,1,4096) fp32
    const float* y     = (const float*)d_in[1];   // (8,2) fp32
    const int*   eps   = (const int*)d_in[2];     // scalar int
    float* out = (float*)d_out;                   // scalar fp32

    // d_out is poisoned before every timed launch; zero it for the atomic mean.
    hipMemsetAsync(out, 0, sizeof(float), stream);
    custom_loss_kernel<<<8, NTHREADS, 0, stream>>>(w_phi, y, eps, out);
}

// Round 2
// 60.713 us; speedup vs baseline: 1.0214x; 1.0214x over previous
//
#include <hip/hip_runtime.h>

#define T 4096
#define B 8
#define CHUNK 64
#define MIN_GAP 5
#define MIN_SIZE 5
#define NEG (-3.402823466e38f)

// One wave (64 lanes) per batch; 8 waves = 512 threads = 1 block = 1 kernel node.
// Lane l owns x[64l .. 64l+63] in registers. Suffix-max of b is:
//   in-lane serial suffix (registers) + cross-lane Kogge-Stone suffix via shfl.
// No LDS scan, no barriers except the final 8-way combine.
__global__ __launch_bounds__(512, 2)
void custom_loss_kernel(const float* __restrict__ w_phi,
                        const float* __restrict__ y,
                        const int* __restrict__ eps_p,
                        float* __restrict__ out) {
    const int t    = threadIdx.x;
    const int wave = t >> 6;   // batch index 0..7
    const int lane = t & 63;

    const float eps = (float)eps_p[0];
    const float y0  = y[wave * 2 + 0];
    const float y1  = y[wave * 2 + 1];
    const float* __restrict__ x = w_phi + (size_t)wave * T + (size_t)lane * CHUNK;

    __shared__ float wred[B];

    // ---- load 64 contiguous floats into registers (float4 x16) ----
    float xr[CHUNK];
    #pragma unroll
    for (int q = 0; q < CHUNK / 4; q++) {
        float4 v = ((const float4*)x)[q];
        xr[4 * q + 0] = v.x;
        xr[4 * q + 1] = v.y;
        xr[4 * q + 2] = v.z;
        xr[4 * q + 3] = v.w;
    }

    const float base = (float)(lane * CHUNK);

    // ---- in-lane suffix max of b over the chunk ----
    float ls[CHUNK];
    {
        float run = NEG;
        #pragma unroll
        for (int j = CHUNK - 1; j >= 0; j--) {
            float fj = base + (float)j;
            float bj = xr[j] + 0.5f * fmaxf(0.0f, fabsf(y1 - fj) - eps);
            run = fmaxf(run, bj);
            ls[j] = run;
        }
    }

    // ---- cross-lane inclusive suffix max of chunk maxima (Kogge-Stone) ----
    float inc = ls[0];
    #pragma unroll
    for (int off = 1; off < 64; off <<= 1) {
        float u = __shfl_down(inc, off, 64);
        inc = (lane + off < 64) ? fmaxf(inc, u) : inc;
    }
    // exclusive: S = max over lanes > l of their chunk maxima
    float S = __shfl_down(inc, 1, 64);
    if (lane == 63) S = NEG;

    // full suffix max at local j is max(ls[j], S).
    // neighbor-lane sm values for the last MIN_SIZE elements of each chunk:
    float nsm[MIN_SIZE];
    #pragma unroll
    for (int k = 0; k < MIN_SIZE; k++) {
        nsm[k] = __shfl_down(fmaxf(ls[k], S), 1, 64);
    }

    // ---- best = max over valid i of a[i] + sm[i+MIN_SIZE] ----
    float best = NEG;
    #pragma unroll
    for (int j = 0; j < CHUNK; j++) {
        float fj = base + (float)j;
        float aj = xr[j] + 0.5f * fmaxf(0.0f, fabsf(y0 - fj) - eps);
        float smv;
        bool valid;
        if (j <= CHUNK - 1 - MIN_SIZE) {       // i+5 stays in this lane's chunk
            smv   = fmaxf(ls[j + MIN_SIZE], S);
            valid = true;
        } else {                               // i+5 falls in next lane's chunk
            smv   = nsm[j - (CHUNK - MIN_SIZE)];
            valid = (lane < 63);               // lane 63 tail: i > T-1-MIN_SIZE, invalid
        }
        if (lane == 0 && j < MIN_GAP) valid = false;   // i >= MIN_GAP
        if (valid) best = fmaxf(best, aj + smv);
    }

    // ---- wave max-reduce ----
    #pragma unroll
    for (int off = 32; off > 0; off >>= 1) {
        best = fmaxf(best, __shfl_down(best, off, 64));
    }

    if (lane == 0) {
        // init = a[1] + b[1+MIN_SIZE]; both indices live in lane 0's chunk
        float a1 = xr[1] + 0.5f * fmaxf(0.0f, fabsf(y0 - 1.0f) - eps);
        float b6 = xr[6] + 0.5f * fmaxf(0.0f, fabsf(y1 - (float)(1 + MIN_SIZE)) - eps);
        wred[wave] = fmaxf(best, a1 + b6);
    }
    __syncthreads();

    if (t == 0) {
        float s = 0.0f;
        #pragma unroll
        for (int k = 0; k < B; k++) s += wred[k];
        out[0] = s * 0.125f;   // mean over B=8
    }
}

extern "C" void kernel_launch(void* const* d_in, const int* in_sizes, int n_in,
                              void* d_out, int out_size, void* d_ws, size_t ws_size,
                              hipStream_t stream) {
    const float* w_phi = (const float*)d_in[0];   // (8,1,4096) fp32
    const float* y     = (const float*)d_in[1];   // (8,2) fp32
    const int*   eps   = (const int*)d_in[2];     // scalar int
    float* out = (float*)d_out;                   // scalar fp32

    custom_loss_kernel<<<1, 512, 0, stream>>>(w_phi, y, eps, out);
}